// Round 2
// baseline (8605.820 us; speedup 1.0000x reference)
//
#include <hip/hip_runtime.h>

#define USER_NUM 200000
#define ITEM_NUM 100000
#define EMB 64

// ---------------------------------------------------------------------------
// SpMM (COO, unsorted): out[rows[e]] += vals[e] * X[cols[e]]
// One thread handles one (edge, 4-dim quad): float4 gather + 4 atomicAdd.
// ---------------------------------------------------------------------------
__global__ __launch_bounds__(256) void spmm_atomic_kernel(
    const int* __restrict__ rows, const int* __restrict__ cols,
    const float* __restrict__ vals, const float* __restrict__ X,
    float* __restrict__ out, int nnz)
{
    int t = blockIdx.x * 256 + threadIdx.x;
    int e = t >> 4;                 // edge index
    if (e >= nnz) return;
    int q = (t & 15) << 2;          // dim offset 0,4,...,60
    int r = rows[e];
    int c = cols[e];
    float v = vals[e];
    float4 x = *reinterpret_cast<const float4*>(X + (size_t)c * EMB + q);
    float* o = out + (size_t)r * EMB + q;
    atomicAdd(o + 0, v * x.x);
    atomicAdd(o + 1, v * x.y);
    atomicAdd(o + 2, v * x.z);
    atomicAdd(o + 3, v * x.w);
}

// ---------------------------------------------------------------------------
// Dense layer: Uout[u,k] = relu( sum_j [agg[u],Uin[u]][j] * W[k][j] + b[k] )
// One wave (64 lanes) per 64 users; lane = user. acc[64] in VGPRs.
// W accessed with wave-uniform indices -> compiler emits s_load (scalar pipe),
// so the VALU streams pure v_fmac with an SGPR operand.
// ---------------------------------------------------------------------------
__global__ __launch_bounds__(64) void dense_relu_kernel(
    const float* __restrict__ agg, const float* __restrict__ Uin,
    const float* __restrict__ W,     // [64][128] row-major (out,in)
    const float* __restrict__ bias,  // [64]
    float* __restrict__ Uout, int nrows)
{
    int lane = threadIdx.x;
    int u = blockIdx.x * 64 + lane;
    if (u >= nrows) return;

    float acc[EMB];
    #pragma unroll
    for (int k = 0; k < EMB; ++k) acc[k] = bias[k];

    const float* rowA = agg + (size_t)u * EMB;
    const float* rowU = Uin + (size_t)u * EMB;

    #pragma unroll 1
    for (int jc = 0; jc < 8; ++jc) {
        const float* src = (jc < 4) ? (rowA + jc * 16) : (rowU + (jc - 4) * 16);
        float4 h0 = reinterpret_cast<const float4*>(src)[0];
        float4 h1 = reinterpret_cast<const float4*>(src)[1];
        float4 h2 = reinterpret_cast<const float4*>(src)[2];
        float4 h3 = reinterpret_cast<const float4*>(src)[3];
        float hbuf[16] = {h0.x,h0.y,h0.z,h0.w, h1.x,h1.y,h1.z,h1.w,
                          h2.x,h2.y,h2.z,h2.w, h3.x,h3.y,h3.z,h3.w};
        const float* wbase = W + jc * 16;
        #pragma unroll
        for (int k = 0; k < EMB; ++k) {
            const float* wr = wbase + (size_t)k * 128;
            #pragma unroll
            for (int j = 0; j < 16; ++j)
                acc[k] = fmaf(hbuf[j], wr[j], acc[k]);
        }
    }

    float* orow = Uout + (size_t)u * EMB;
    #pragma unroll
    for (int kc = 0; kc < 16; ++kc) {
        float4 o;
        o.x = fmaxf(acc[kc*4+0], 0.f);
        o.y = fmaxf(acc[kc*4+1], 0.f);
        o.z = fmaxf(acc[kc*4+2], 0.f);
        o.w = fmaxf(acc[kc*4+3], 0.f);
        reinterpret_cast<float4*>(orow)[kc] = o;
    }
}

extern "C" void kernel_launch(void* const* d_in, const int* in_sizes, int n_in,
                              void* d_out, int out_size, void* d_ws, size_t ws_size,
                              hipStream_t stream) {
    const float* user_emb = (const float*)d_in[0];   // [200000,64]
    const float* item_emb = (const float*)d_in[1];   // [100000,64]
    const float* W        = (const float*)d_in[2];   // [2,64,128]
    const float* b        = (const float*)d_in[3];   // [2,64]
    const int*   s_rows   = (const int*)d_in[4];
    const int*   s_cols   = (const int*)d_in[5];
    const float* s_vals   = (const float*)d_in[6];
    const int*   r_rows   = (const int*)d_in[7];
    const int*   r_cols   = (const int*)d_in[8];
    const float* r_vals   = (const float*)d_in[9];

    int ne_s = in_sizes[4];
    int ne_r = in_sizes[7];

    float* out      = (float*)d_out;
    float* user_out = out;                                  // [200000,64]
    float* item_out = out + (size_t)USER_NUM * EMB;         // [100000,64]
    float* agg      = (float*)d_ws;                         // [200000,64] scratch
    size_t aggBytes = (size_t)USER_NUM * EMB * sizeof(float);

    dim3 blk(256);
    int spmmBlocksS = (ne_s * 16 + 255) / 256;
    int spmmBlocksR = (ne_r * 16 + 255) / 256;
    int denseBlocks = (USER_NUM + 63) / 64;

    // Layer 0: agg = S @ user_emb ; U1 = relu([agg,user_emb] @ W0^T + b0) -> user_out
    hipMemsetAsync(agg, 0, aggBytes, stream);
    spmm_atomic_kernel<<<spmmBlocksS, blk, 0, stream>>>(s_rows, s_cols, s_vals,
                                                        user_emb, agg, ne_s);
    dense_relu_kernel<<<denseBlocks, 64, 0, stream>>>(agg, user_emb, W, b,
                                                      user_out, USER_NUM);

    // Layer 1: agg = S @ U1 ; U2 = relu([agg,U1] @ W1^T + b1) -> user_out (in-place)
    hipMemsetAsync(agg, 0, aggBytes, stream);
    spmm_atomic_kernel<<<spmmBlocksS, blk, 0, stream>>>(s_rows, s_cols, s_vals,
                                                        user_out, agg, ne_s);
    dense_relu_kernel<<<denseBlocks, 64, 0, stream>>>(agg, user_out,
                                                      W + 64 * 128, b + 64,
                                                      user_out, USER_NUM);

    // user_all = U2 + R @ item_emb (atomic accumulate directly into output)
    spmm_atomic_kernel<<<spmmBlocksR, blk, 0, stream>>>(r_rows, r_cols, r_vals,
                                                        item_emb, user_out, ne_r);

    // item_all = item_emb (passthrough)
    hipMemcpyAsync(item_out, item_emb, (size_t)ITEM_NUM * EMB * sizeof(float),
                   hipMemcpyDeviceToDevice, stream);
}

// Round 3
// 1920.167 us; speedup vs baseline: 4.4818x; 4.4818x over previous
//
#include <hip/hip_runtime.h>

#define USER_NUM 200000
#define ITEM_NUM 100000
#define EMB 64

#define SCAN_T 256
#define SCAN_E 8
#define SCAN_TILE (SCAN_T * SCAN_E)

// ---------------------------------------------------------------------------
// CSR build step 1: histogram of row indices (int atomics, 800KB L2-resident)
// ---------------------------------------------------------------------------
__global__ __launch_bounds__(256) void hist_kernel(
    const int* __restrict__ rows, int nnz, int* __restrict__ cnt)
{
    int e = blockIdx.x * 256 + threadIdx.x;
    if (e >= nnz) return;
    atomicAdd(&cnt[rows[e]], 1);
}

// ---------------------------------------------------------------------------
// CSR build step 2a: per-tile (2048 elems) sums -> partials[nblocks]
// ---------------------------------------------------------------------------
__global__ __launch_bounds__(SCAN_T) void block_sum_kernel(
    const int* __restrict__ cnt, int n, int* __restrict__ partials)
{
    __shared__ int sm[SCAN_T];
    int tid = threadIdx.x;
    int base = blockIdx.x * SCAN_TILE + tid * SCAN_E;
    int s = 0;
    #pragma unroll
    for (int j = 0; j < SCAN_E; ++j) {
        int i = base + j;
        if (i < n) s += cnt[i];
    }
    sm[tid] = s; __syncthreads();
    for (int off = SCAN_T / 2; off > 0; off >>= 1) {
        if (tid < off) sm[tid] += sm[tid + off];
        __syncthreads();
    }
    if (tid == 0) partials[blockIdx.x] = sm[0];
}

// ---------------------------------------------------------------------------
// CSR build step 2b: single-block exclusive scan of partials (nblocks<=256)
// ---------------------------------------------------------------------------
__global__ __launch_bounds__(SCAN_T) void scan_partials_kernel(
    int* __restrict__ partials, int nblocks)
{
    __shared__ int sm[SCAN_T];
    int tid = threadIdx.x;
    int v = (tid < nblocks) ? partials[tid] : 0;
    sm[tid] = v; __syncthreads();
    for (int off = 1; off < SCAN_T; off <<= 1) {
        int a = (tid >= off) ? sm[tid - off] : 0;
        __syncthreads();
        sm[tid] += a;
        __syncthreads();
    }
    if (tid < nblocks) partials[tid] = sm[tid] - v;   // exclusive
}

// ---------------------------------------------------------------------------
// CSR build step 2c: per-tile exclusive scan + global offset -> row_ptr
// thread t owns SCAN_E consecutive elements. Also writes row_ptr[n].
// ---------------------------------------------------------------------------
__global__ __launch_bounds__(SCAN_T) void scan_tile_kernel(
    const int* __restrict__ cnt, int n, const int* __restrict__ partials,
    int* __restrict__ row_ptr)
{
    __shared__ int sm[SCAN_T];
    int tid = threadIdx.x;
    int base = blockIdx.x * SCAN_TILE + tid * SCAN_E;
    int local[SCAN_E];
    int s = 0;
    #pragma unroll
    for (int j = 0; j < SCAN_E; ++j) {
        int i = base + j;
        local[j] = (i < n) ? cnt[i] : 0;
        s += local[j];
    }
    sm[tid] = s; __syncthreads();
    for (int off = 1; off < SCAN_T; off <<= 1) {
        int a = (tid >= off) ? sm[tid - off] : 0;
        __syncthreads();
        sm[tid] += a;
        __syncthreads();
    }
    int run = partials[blockIdx.x] + (sm[tid] - s);   // exclusive prefix
    #pragma unroll
    for (int j = 0; j < SCAN_E; ++j) {
        int i = base + j;
        if (i < n) row_ptr[i] = run;
        run += local[j];
        if (i == n - 1) row_ptr[n] = run;
    }
}

// ---------------------------------------------------------------------------
// CSR build step 3: scatter edges into row-sorted order (cursor pre-zeroed)
// ---------------------------------------------------------------------------
__global__ __launch_bounds__(256) void scatter_kernel(
    const int* __restrict__ rows, const int* __restrict__ cols,
    const float* __restrict__ vals, int nnz,
    const int* __restrict__ row_ptr, int* __restrict__ cursor,
    int* __restrict__ ecols, float* __restrict__ evals)
{
    int e = blockIdx.x * 256 + threadIdx.x;
    if (e >= nnz) return;
    int r = rows[e];
    int p = row_ptr[r] + atomicAdd(&cursor[r], 1);
    ecols[p] = cols[e];
    evals[p] = vals[e];
}

// ---------------------------------------------------------------------------
// CSR SpMM: out[row] = (addin ? addin[row] : 0) + sum_e vals[e]*X[cols[e]]
// One wave per row, lane = dim. Each gather is one coalesced 256B row read.
// Zero atomics; each output element written exactly once.
// ---------------------------------------------------------------------------
__global__ __launch_bounds__(256) void spmm_csr_kernel(
    const int* __restrict__ row_ptr, const int* __restrict__ ecols,
    const float* __restrict__ evals, const float* __restrict__ X,
    const float* __restrict__ addin, float* __restrict__ out, int n_rows)
{
    int gid = blockIdx.x * 256 + threadIdx.x;
    int row = gid >> 6;
    int lane = gid & 63;
    if (row >= n_rows) return;
    int beg = row_ptr[row], end = row_ptr[row + 1];
    float acc = addin ? addin[(size_t)row * EMB + lane] : 0.0f;
    int i = beg;
    for (; i + 1 < end; i += 2) {          // 2-way unroll: overlap gather latency
        int   c0 = ecols[i],   c1 = ecols[i + 1];
        float v0 = evals[i],   v1 = evals[i + 1];
        float x0 = X[(size_t)c0 * EMB + lane];
        float x1 = X[(size_t)c1 * EMB + lane];
        acc = fmaf(v0, x0, acc);
        acc = fmaf(v1, x1, acc);
    }
    if (i < end) {
        int c = ecols[i];
        acc = fmaf(evals[i], X[(size_t)c * EMB + lane], acc);
    }
    out[(size_t)row * EMB + lane] = acc;
}

// ---------------------------------------------------------------------------
// Fallback SpMM (round-2 atomic path) — used only if ws_size too small.
// ---------------------------------------------------------------------------
__global__ __launch_bounds__(256) void spmm_atomic_kernel(
    const int* __restrict__ rows, const int* __restrict__ cols,
    const float* __restrict__ vals, const float* __restrict__ X,
    float* __restrict__ out, int nnz)
{
    int t = blockIdx.x * 256 + threadIdx.x;
    int e = t >> 4;
    if (e >= nnz) return;
    int q = (t & 15) << 2;
    int r = rows[e];
    int c = cols[e];
    float v = vals[e];
    float4 x = *reinterpret_cast<const float4*>(X + (size_t)c * EMB + q);
    float* o = out + (size_t)r * EMB + q;
    atomicAdd(o + 0, v * x.x);
    atomicAdd(o + 1, v * x.y);
    atomicAdd(o + 2, v * x.z);
    atomicAdd(o + 3, v * x.w);
}

// ---------------------------------------------------------------------------
// Dense layer: Uout[u,k] = relu( sum_j [agg[u],Uin[u]][j] * W[k][j] + b[k] )
// 256-thread blocks (4 waves) for occupancy; lane = user; W wave-uniform.
// ---------------------------------------------------------------------------
__global__ __launch_bounds__(256) void dense_relu_kernel(
    const float* __restrict__ agg, const float* __restrict__ Uin,
    const float* __restrict__ W,     // [64][128] row-major (out,in)
    const float* __restrict__ bias,  // [64]
    float* __restrict__ Uout, int nrows)
{
    int u = blockIdx.x * 256 + threadIdx.x;
    if (u >= nrows) return;

    float acc[EMB];
    #pragma unroll
    for (int k = 0; k < EMB; ++k) acc[k] = bias[k];

    const float* rowA = agg + (size_t)u * EMB;
    const float* rowU = Uin + (size_t)u * EMB;

    #pragma unroll 1
    for (int jc = 0; jc < 8; ++jc) {
        const float* src = (jc < 4) ? (rowA + jc * 16) : (rowU + (jc - 4) * 16);
        float4 h0 = reinterpret_cast<const float4*>(src)[0];
        float4 h1 = reinterpret_cast<const float4*>(src)[1];
        float4 h2 = reinterpret_cast<const float4*>(src)[2];
        float4 h3 = reinterpret_cast<const float4*>(src)[3];
        float hbuf[16] = {h0.x,h0.y,h0.z,h0.w, h1.x,h1.y,h1.z,h1.w,
                          h2.x,h2.y,h2.z,h2.w, h3.x,h3.y,h3.z,h3.w};
        const float* wbase = W + jc * 16;
        #pragma unroll
        for (int k = 0; k < EMB; ++k) {
            const float* wr = wbase + (size_t)k * 128;
            #pragma unroll
            for (int j = 0; j < 16; ++j)
                acc[k] = fmaf(hbuf[j], wr[j], acc[k]);
        }
    }

    float* orow = Uout + (size_t)u * EMB;
    #pragma unroll
    for (int kc = 0; kc < 16; ++kc) {
        float4 o;
        o.x = fmaxf(acc[kc*4+0], 0.f);
        o.y = fmaxf(acc[kc*4+1], 0.f);
        o.z = fmaxf(acc[kc*4+2], 0.f);
        o.w = fmaxf(acc[kc*4+3], 0.f);
        reinterpret_cast<float4*>(orow)[kc] = o;
    }
}

// ---------------------------------------------------------------------------
static void build_csr(const int* rows, const int* cols, const float* vals,
                      int nnz, int n_rows, int* cnt, int* partials,
                      int* row_ptr, int* ecols, float* evals,
                      hipStream_t stream)
{
    int nScan = (n_rows + SCAN_TILE - 1) / SCAN_TILE;   // 98 for 200000
    hipMemsetAsync(cnt, 0, (size_t)n_rows * sizeof(int), stream);
    hist_kernel<<<(nnz + 255) / 256, 256, 0, stream>>>(rows, nnz, cnt);
    block_sum_kernel<<<nScan, SCAN_T, 0, stream>>>(cnt, n_rows, partials);
    scan_partials_kernel<<<1, SCAN_T, 0, stream>>>(partials, nScan);
    scan_tile_kernel<<<nScan, SCAN_T, 0, stream>>>(cnt, n_rows, partials, row_ptr);
    hipMemsetAsync(cnt, 0, (size_t)n_rows * sizeof(int), stream);
    scatter_kernel<<<(nnz + 255) / 256, 256, 0, stream>>>(rows, cols, vals, nnz,
                                                          row_ptr, cnt, ecols, evals);
}

extern "C" void kernel_launch(void* const* d_in, const int* in_sizes, int n_in,
                              void* d_out, int out_size, void* d_ws, size_t ws_size,
                              hipStream_t stream) {
    const float* user_emb = (const float*)d_in[0];   // [200000,64]
    const float* item_emb = (const float*)d_in[1];   // [100000,64]
    const float* W        = (const float*)d_in[2];   // [2,64,128]
    const float* b        = (const float*)d_in[3];   // [2,64]
    const int*   s_rows   = (const int*)d_in[4];
    const int*   s_cols   = (const int*)d_in[5];
    const float* s_vals   = (const float*)d_in[6];
    const int*   r_rows   = (const int*)d_in[7];
    const int*   r_cols   = (const int*)d_in[8];
    const float* r_vals   = (const float*)d_in[9];

    int ne_s = in_sizes[4];
    int ne_r = in_sizes[7];

    float* out      = (float*)d_out;
    float* user_out = out;                                  // [200000,64]
    float* item_out = out + (size_t)USER_NUM * EMB;         // [100000,64]

    // ---- workspace layout ----
    char* w = (char*)d_ws;
    float* agg      = (float*)w;  w += (size_t)USER_NUM * EMB * 4;
    int*   s_rowptr = (int*)w;    w += (size_t)(USER_NUM + 1) * 4;
    int*   r_rowptr = (int*)w;    w += (size_t)(USER_NUM + 1) * 4;
    int*   cnt      = (int*)w;    w += (size_t)USER_NUM * 4;      // hist + cursor
    int*   partials = (int*)w;    w += 256 * 4;
    int*   s_ecols  = (int*)w;    w += (size_t)ne_s * 4;
    float* s_evals  = (float*)w;  w += (size_t)ne_s * 4;
    int*   r_ecols  = (int*)w;    w += (size_t)ne_r * 4;
    float* r_evals  = (float*)w;  w += (size_t)ne_r * 4;
    size_t needed = (size_t)(w - (char*)d_ws);

    size_t aggBytes = (size_t)USER_NUM * EMB * sizeof(float);
    int denseBlocks = (USER_NUM + 255) / 256;
    int spmmBlocks  = (USER_NUM * 64 + 255) / 256;   // 1 wave per row

    if (ws_size >= needed) {
        // ---- CSR path (no float atomics anywhere) ----
        build_csr(s_rows, s_cols, s_vals, ne_s, USER_NUM,
                  cnt, partials, s_rowptr, s_ecols, s_evals, stream);
        build_csr(r_rows, r_cols, r_vals, ne_r, USER_NUM,
                  cnt, partials, r_rowptr, r_ecols, r_evals, stream);

        // Layer 0
        spmm_csr_kernel<<<spmmBlocks, 256, 0, stream>>>(
            s_rowptr, s_ecols, s_evals, user_emb, nullptr, agg, USER_NUM);
        dense_relu_kernel<<<denseBlocks, 256, 0, stream>>>(
            agg, user_emb, W, b, user_out, USER_NUM);

        // Layer 1 (in-place on user_out)
        spmm_csr_kernel<<<spmmBlocks, 256, 0, stream>>>(
            s_rowptr, s_ecols, s_evals, user_out, nullptr, agg, USER_NUM);
        dense_relu_kernel<<<denseBlocks, 256, 0, stream>>>(
            agg, user_out, W + 64 * 128, b + 64, user_out, USER_NUM);

        // user_all = U2 + R @ item_emb  (read-add-write per element, in-place safe)
        spmm_csr_kernel<<<spmmBlocks, 256, 0, stream>>>(
            r_rowptr, r_ecols, r_evals, item_emb, user_out, user_out, USER_NUM);
    } else {
        // ---- fallback: round-2 atomic path (needs only agg) ----
        int spmmBlocksS = (ne_s * 16 + 255) / 256;
        int spmmBlocksR = (ne_r * 16 + 255) / 256;
        hipMemsetAsync(agg, 0, aggBytes, stream);
        spmm_atomic_kernel<<<spmmBlocksS, 256, 0, stream>>>(s_rows, s_cols, s_vals,
                                                            user_emb, agg, ne_s);
        dense_relu_kernel<<<denseBlocks, 256, 0, stream>>>(agg, user_emb, W, b,
                                                           user_out, USER_NUM);
        hipMemsetAsync(agg, 0, aggBytes, stream);
        spmm_atomic_kernel<<<spmmBlocksS, 256, 0, stream>>>(s_rows, s_cols, s_vals,
                                                            user_out, agg, ne_s);
        dense_relu_kernel<<<denseBlocks, 256, 0, stream>>>(agg, user_out,
                                                           W + 64 * 128, b + 64,
                                                           user_out, USER_NUM);
        spmm_atomic_kernel<<<spmmBlocksR, 256, 0, stream>>>(r_rows, r_cols, r_vals,
                                                            item_emb, user_out, ne_r);
    }

    // item_all = item_emb (passthrough)
    hipMemcpyAsync(item_out, item_emb, (size_t)ITEM_NUM * EMB * sizeof(float),
                   hipMemcpyDeviceToDevice, stream);
}

// Round 4
// 1537.807 us; speedup vs baseline: 5.5962x; 1.2486x over previous
//
#include <hip/hip_runtime.h>

#define USER_NUM 200000
#define ITEM_NUM 100000
#define EMB 64

#define SCAN_T 256
#define SCAN_E 8
#define SCAN_TILE (SCAN_T * SCAN_E)

// ---------------------------------------------------------------------------
// CSR build step 1: histogram of row indices (int atomics, 800KB L2-resident)
// ---------------------------------------------------------------------------
__global__ __launch_bounds__(256) void hist_kernel(
    const int* __restrict__ rows, int nnz, int* __restrict__ cnt)
{
    int e = blockIdx.x * 256 + threadIdx.x;
    if (e >= nnz) return;
    atomicAdd(&cnt[rows[e]], 1);
}

// ---------------------------------------------------------------------------
// CSR build step 2a: per-tile (2048 elems) sums -> partials[nblocks]
// ---------------------------------------------------------------------------
__global__ __launch_bounds__(SCAN_T) void block_sum_kernel(
    const int* __restrict__ cnt, int n, int* __restrict__ partials)
{
    __shared__ int sm[SCAN_T];
    int tid = threadIdx.x;
    int base = blockIdx.x * SCAN_TILE + tid * SCAN_E;
    int s = 0;
    #pragma unroll
    for (int j = 0; j < SCAN_E; ++j) {
        int i = base + j;
        if (i < n) s += cnt[i];
    }
    sm[tid] = s; __syncthreads();
    for (int off = SCAN_T / 2; off > 0; off >>= 1) {
        if (tid < off) sm[tid] += sm[tid + off];
        __syncthreads();
    }
    if (tid == 0) partials[blockIdx.x] = sm[0];
}

// ---------------------------------------------------------------------------
// CSR build step 2b: single-block exclusive scan of partials (nblocks<=256)
// ---------------------------------------------------------------------------
__global__ __launch_bounds__(SCAN_T) void scan_partials_kernel(
    int* __restrict__ partials, int nblocks)
{
    __shared__ int sm[SCAN_T];
    int tid = threadIdx.x;
    int v = (tid < nblocks) ? partials[tid] : 0;
    sm[tid] = v; __syncthreads();
    for (int off = 1; off < SCAN_T; off <<= 1) {
        int a = (tid >= off) ? sm[tid - off] : 0;
        __syncthreads();
        sm[tid] += a;
        __syncthreads();
    }
    if (tid < nblocks) partials[tid] = sm[tid] - v;   // exclusive
}

// ---------------------------------------------------------------------------
// CSR build step 2c: per-tile exclusive scan + global offset -> row_ptr
// Also initializes cursor[i] = row_ptr[i] (scatter cursor, saves a memset).
// ---------------------------------------------------------------------------
__global__ __launch_bounds__(SCAN_T) void scan_tile_kernel(
    const int* __restrict__ cnt, int n, const int* __restrict__ partials,
    int* __restrict__ row_ptr, int* __restrict__ cursor)
{
    __shared__ int sm[SCAN_T];
    int tid = threadIdx.x;
    int base = blockIdx.x * SCAN_TILE + tid * SCAN_E;
    int local[SCAN_E];
    int s = 0;
    #pragma unroll
    for (int j = 0; j < SCAN_E; ++j) {
        int i = base + j;
        local[j] = (i < n) ? cnt[i] : 0;
        s += local[j];
    }
    sm[tid] = s; __syncthreads();
    for (int off = 1; off < SCAN_T; off <<= 1) {
        int a = (tid >= off) ? sm[tid - off] : 0;
        __syncthreads();
        sm[tid] += a;
        __syncthreads();
    }
    int run = partials[blockIdx.x] + (sm[tid] - s);   // exclusive prefix
    #pragma unroll
    for (int j = 0; j < SCAN_E; ++j) {
        int i = base + j;
        if (i < n) { row_ptr[i] = run; cursor[i] = run; }
        run += local[j];
        if (i == n - 1) row_ptr[n] = run;
    }
}

// ---------------------------------------------------------------------------
// CSR build step 3: scatter edges into row-sorted order.
// (col,val) paired into one int2 -> ONE 8B random store per edge (halves the
// 64B-line write amplification vs two 4B stores into separate arrays).
// ---------------------------------------------------------------------------
__global__ __launch_bounds__(256) void scatter_kernel(
    const int* __restrict__ rows, const int* __restrict__ cols,
    const float* __restrict__ vals, int nnz,
    int* __restrict__ cursor, int2* __restrict__ epairs)
{
    int e = blockIdx.x * 256 + threadIdx.x;
    if (e >= nnz) return;
    int r = rows[e];
    int p = atomicAdd(&cursor[r], 1);
    epairs[p] = make_int2(cols[e], __float_as_int(vals[e]));
}

// ---------------------------------------------------------------------------
// CSR SpMM: out[row] = (addin ? addin[row] : 0) + sum_e val*X[col]
// One wave per row, lane = dim. 8B paired edge loads, 4-way unroll.
// ---------------------------------------------------------------------------
__global__ __launch_bounds__(256) void spmm_csr_kernel(
    const int* __restrict__ row_ptr, const int2* __restrict__ epairs,
    const float* __restrict__ X, const float* __restrict__ addin,
    float* __restrict__ out, int n_rows)
{
    int gid = blockIdx.x * 256 + threadIdx.x;
    int row = gid >> 6;
    int lane = gid & 63;
    if (row >= n_rows) return;
    int beg = row_ptr[row], end = row_ptr[row + 1];
    float acc = addin ? addin[(size_t)row * EMB + lane] : 0.0f;
    int i = beg;
    for (; i + 4 <= end; i += 4) {
        int2 e0 = epairs[i], e1 = epairs[i+1], e2 = epairs[i+2], e3 = epairs[i+3];
        float x0 = X[(size_t)e0.x * EMB + lane];
        float x1 = X[(size_t)e1.x * EMB + lane];
        float x2 = X[(size_t)e2.x * EMB + lane];
        float x3 = X[(size_t)e3.x * EMB + lane];
        acc = fmaf(__int_as_float(e0.y), x0, acc);
        acc = fmaf(__int_as_float(e1.y), x1, acc);
        acc = fmaf(__int_as_float(e2.y), x2, acc);
        acc = fmaf(__int_as_float(e3.y), x3, acc);
    }
    for (; i < end; ++i) {
        int2 e = epairs[i];
        acc = fmaf(__int_as_float(e.y), X[(size_t)e.x * EMB + lane], acc);
    }
    out[(size_t)row * EMB + lane] = acc;
}

// ---------------------------------------------------------------------------
// Fallback SpMM (atomic path) — used only if ws_size too small.
// ---------------------------------------------------------------------------
__global__ __launch_bounds__(256) void spmm_atomic_kernel(
    const int* __restrict__ rows, const int* __restrict__ cols,
    const float* __restrict__ vals, const float* __restrict__ X,
    float* __restrict__ out, int nnz)
{
    int t = blockIdx.x * 256 + threadIdx.x;
    int e = t >> 4;
    if (e >= nnz) return;
    int q = (t & 15) << 2;
    int r = rows[e];
    int c = cols[e];
    float v = vals[e];
    float4 x = *reinterpret_cast<const float4*>(X + (size_t)c * EMB + q);
    float* o = out + (size_t)r * EMB + q;
    atomicAdd(o + 0, v * x.x);
    atomicAdd(o + 1, v * x.y);
    atomicAdd(o + 2, v * x.z);
    atomicAdd(o + 3, v * x.w);
}

// ---------------------------------------------------------------------------
// Dense layer: Uout[u,k] = relu( sum_j [agg[u],Uin[u]][j] * W[k][j] + b[k] )
// W (32KB) + bias staged in LDS; wave-uniform ds_read_b128 (broadcast).
// Thread owns 2 users, full acc[2][64] in VGPRs (~170) under an explicit
// (256,2) bound: 256-VGPR cap -> no spill; grid 512 = exactly 2 blocks/CU.
// Per ds_read_b128 (12cy) -> 8 fma (16cy): VALU-bound.
// All h reads precede all stores -> safe for in-place layer 1.
// ---------------------------------------------------------------------------
#define DENSE_BLOCKS 512
#define DENSE_SPAN (DENSE_BLOCKS * 256)   // 131072

__global__ __launch_bounds__(256, 2) void dense_relu_kernel(
    const float* __restrict__ agg, const float* __restrict__ Uin,
    const float* __restrict__ W,     // [64][128] row-major (out,in)
    const float* __restrict__ bias,  // [64]
    float* __restrict__ Uout, int nrows)
{
    __shared__ float Wl[64 * 128 + 64];
    int tid = threadIdx.x;
    #pragma unroll
    for (int i = 0; i < 8; ++i) {
        int idx = tid + i * 256;
        reinterpret_cast<float4*>(Wl)[idx] = reinterpret_cast<const float4*>(W)[idx];
    }
    if (tid < 64) Wl[8192 + tid] = bias[tid];
    __syncthreads();

    int gid = blockIdx.x * 256 + tid;
    int u0 = gid;
    int u1 = gid + DENSE_SPAN;
    bool ok1 = (u1 < nrows);
    if (u0 >= nrows) return;

    float acc[2][EMB];
    #pragma unroll
    for (int k = 0; k < EMB; ++k) {
        float bv = Wl[8192 + k];
        acc[0][k] = bv;
        acc[1][k] = bv;
    }

    #pragma unroll 1
    for (int half = 0; half < 2; ++half) {
        const float* __restrict__ src = half ? Uin : agg;
        const float4* r0 = reinterpret_cast<const float4*>(src + (size_t)u0 * EMB);
        const float4* r1 = ok1 ? reinterpret_cast<const float4*>(src + (size_t)u1 * EMB)
                               : r0;
        #pragma unroll 1
        for (int jq = 0; jq < 16; ++jq) {
            float4 h0 = r0[jq];
            float4 h1 = r1[jq];
            #pragma unroll
            for (int k = 0; k < EMB; ++k) {
                float4 wv = *reinterpret_cast<const float4*>(
                    Wl + k * 128 + half * 64 + jq * 4);
                acc[0][k] = fmaf(h0.x, wv.x, acc[0][k]);
                acc[0][k] = fmaf(h0.y, wv.y, acc[0][k]);
                acc[0][k] = fmaf(h0.z, wv.z, acc[0][k]);
                acc[0][k] = fmaf(h0.w, wv.w, acc[0][k]);
                acc[1][k] = fmaf(h1.x, wv.x, acc[1][k]);
                acc[1][k] = fmaf(h1.y, wv.y, acc[1][k]);
                acc[1][k] = fmaf(h1.z, wv.z, acc[1][k]);
                acc[1][k] = fmaf(h1.w, wv.w, acc[1][k]);
            }
        }
    }

    {
        float* orow = Uout + (size_t)u0 * EMB;
        #pragma unroll
        for (int q = 0; q < 16; ++q) {
            float4 o;
            o.x = fmaxf(acc[0][q*4+0], 0.f);
            o.y = fmaxf(acc[0][q*4+1], 0.f);
            o.z = fmaxf(acc[0][q*4+2], 0.f);
            o.w = fmaxf(acc[0][q*4+3], 0.f);
            reinterpret_cast<float4*>(orow)[q] = o;
        }
    }
    if (ok1) {
        float* orow = Uout + (size_t)u1 * EMB;
        #pragma unroll
        for (int q = 0; q < 16; ++q) {
            float4 o;
            o.x = fmaxf(acc[1][q*4+0], 0.f);
            o.y = fmaxf(acc[1][q*4+1], 0.f);
            o.z = fmaxf(acc[1][q*4+2], 0.f);
            o.w = fmaxf(acc[1][q*4+3], 0.f);
            reinterpret_cast<float4*>(orow)[q] = o;
        }
    }
}

// ---------------------------------------------------------------------------
static void build_csr(const int* rows, const int* cols, const float* vals,
                      int nnz, int n_rows, int* cnt, int* partials,
                      int* row_ptr, int2* epairs, hipStream_t stream)
{
    int nScan = (n_rows + SCAN_TILE - 1) / SCAN_TILE;   // 98 for 200000
    hipMemsetAsync(cnt, 0, (size_t)n_rows * sizeof(int), stream);
    hist_kernel<<<(nnz + 255) / 256, 256, 0, stream>>>(rows, nnz, cnt);
    block_sum_kernel<<<nScan, SCAN_T, 0, stream>>>(cnt, n_rows, partials);
    scan_partials_kernel<<<1, SCAN_T, 0, stream>>>(partials, nScan);
    // writes row_ptr AND pre-inits cursor (reuses cnt buffer as cursor)
    scan_tile_kernel<<<nScan, SCAN_T, 0, stream>>>(cnt, n_rows, partials,
                                                   row_ptr, cnt);
    scatter_kernel<<<(nnz + 255) / 256, 256, 0, stream>>>(rows, cols, vals, nnz,
                                                          cnt, epairs);
}

extern "C" void kernel_launch(void* const* d_in, const int* in_sizes, int n_in,
                              void* d_out, int out_size, void* d_ws, size_t ws_size,
                              hipStream_t stream) {
    const float* user_emb = (const float*)d_in[0];   // [200000,64]
    const float* item_emb = (const float*)d_in[1];   // [100000,64]
    const float* W        = (const float*)d_in[2];   // [2,64,128]
    const float* b        = (const float*)d_in[3];   // [2,64]
    const int*   s_rows   = (const int*)d_in[4];
    const int*   s_cols   = (const int*)d_in[5];
    const float* s_vals   = (const float*)d_in[6];
    const int*   r_rows   = (const int*)d_in[7];
    const int*   r_cols   = (const int*)d_in[8];
    const float* r_vals   = (const float*)d_in[9];

    int ne_s = in_sizes[4];
    int ne_r = in_sizes[7];

    float* out      = (float*)d_out;
    float* user_out = out;                                  // [200000,64]
    float* item_out = out + (size_t)USER_NUM * EMB;         // [100000,64]

    // ---- workspace layout ----
    char* w = (char*)d_ws;
    float* agg      = (float*)w;  w += (size_t)USER_NUM * EMB * 4;
    int*   s_rowptr = (int*)w;    w += (size_t)(USER_NUM + 1) * 4;
    int*   r_rowptr = (int*)w;    w += (size_t)(USER_NUM + 1) * 4;
    int*   cnt      = (int*)w;    w += (size_t)USER_NUM * 4;      // hist + cursor
    int*   partials = (int*)w;    w += 256 * 4;
    int2*  s_epairs = (int2*)w;   w += (size_t)ne_s * 8;
    int2*  r_epairs = (int2*)w;   w += (size_t)ne_r * 8;
    size_t needed = (size_t)(w - (char*)d_ws);

    size_t aggBytes = (size_t)USER_NUM * EMB * sizeof(float);
    int spmmBlocks  = (USER_NUM * 64 + 255) / 256;   // 1 wave per row

    if (ws_size >= needed) {
        // ---- CSR path (no float atomics anywhere) ----
        build_csr(s_rows, s_cols, s_vals, ne_s, USER_NUM,
                  cnt, partials, s_rowptr, s_epairs, stream);
        build_csr(r_rows, r_cols, r_vals, ne_r, USER_NUM,
                  cnt, partials, r_rowptr, r_epairs, stream);

        // Layer 0
        spmm_csr_kernel<<<spmmBlocks, 256, 0, stream>>>(
            s_rowptr, s_epairs, user_emb, nullptr, agg, USER_NUM);
        dense_relu_kernel<<<DENSE_BLOCKS, 256, 0, stream>>>(
            agg, user_emb, W, b, user_out, USER_NUM);

        // Layer 1 (in-place on user_out)
        spmm_csr_kernel<<<spmmBlocks, 256, 0, stream>>>(
            s_rowptr, s_epairs, user_out, nullptr, agg, USER_NUM);
        dense_relu_kernel<<<DENSE_BLOCKS, 256, 0, stream>>>(
            agg, user_out, W + 64 * 128, b + 64, user_out, USER_NUM);

        // user_all = U2 + R @ item_emb
        spmm_csr_kernel<<<spmmBlocks, 256, 0, stream>>>(
            r_rowptr, r_epairs, item_emb, user_out, user_out, USER_NUM);
    } else {
        // ---- fallback: atomic path (needs only agg) ----
        int spmmBlocksS = (ne_s * 16 + 255) / 256;
        int spmmBlocksR = (ne_r * 16 + 255) / 256;
        hipMemsetAsync(agg, 0, aggBytes, stream);
        spmm_atomic_kernel<<<spmmBlocksS, 256, 0, stream>>>(s_rows, s_cols, s_vals,
                                                            user_emb, agg, ne_s);
        dense_relu_kernel<<<DENSE_BLOCKS, 256, 0, stream>>>(agg, user_emb, W, b,
                                                            user_out, USER_NUM);
        hipMemsetAsync(agg, 0, aggBytes, stream);
        spmm_atomic_kernel<<<spmmBlocksS, 256, 0, stream>>>(s_rows, s_cols, s_vals,
                                                            user_out, agg, ne_s);
        dense_relu_kernel<<<DENSE_BLOCKS, 256, 0, stream>>>(agg, user_out,
                                                            W + 64 * 128, b + 64,
                                                            user_out, USER_NUM);
        spmm_atomic_kernel<<<spmmBlocksR, 256, 0, stream>>>(r_rows, r_cols, r_vals,
                                                            item_emb, user_out, ne_r);
    }

    // item_all = item_emb (passthrough)
    hipMemcpyAsync(item_out, item_emb, (size_t)ITEM_NUM * EMB * sizeof(float),
                   hipMemcpyDeviceToDevice, stream);
}